// Round 2
// baseline (731.917 us; speedup 1.0000x reference)
//
#include <hip/hip_runtime.h>

// CapsuleLinear dynamic routing, fully fused, fp32.
// N=64, I=256 in_caps, O=128 out_caps, K=16, L=32, 3 iters.
//
// Grid: 256 blocks = (o 0..127) x (n-half 0..1), 512 threads.
// Round 2: 16-i stages -> LDS 78.5 KB -> 2 blocks/CU (was 1), smaller acc tile,
// 1 exp per thread per stage (was 8). Weight slice (512 KB/o) streamed from
// L2/LLC 5x; x staged in LDS (prob-weighted for s-pass, raw for delta-pass).

#define ICAPS 256
#define OCAPS 128
#define KLEN  16
#define LLEN  32
#define TN    32
#define LGS   257        // logits row stride (pad +1)
#define XROW  20         // xt per-n stride: 16 k + 4 pad
#define XIST  644        // xt per-i stride: 32*20 + 4
#define SVS   33         // s/v row stride
#define NSTG  16         // i per stage
#define NSTEP (ICAPS / NSTG)

__global__ __launch_bounds__(512, 4)
void caps_route(const float* __restrict__ xg_all,
                const float* __restrict__ wg_all,
                float* __restrict__ out) {
    __shared__ float lg[TN * LGS];       // 32.9 KB logits
    __shared__ float xt[NSTG * XIST];    // 41.2 KB x staging / reduce buffer
    __shared__ float sv[TN * SVS];       // 4.2 KB s then v
    __shared__ float stm[TN];
    __shared__ float sti[TN];

    const int t   = threadIdx.x;
    const int o   = blockIdx.x >> 1;
    const int n0  = (blockIdx.x & 1) * TN;
    const int isp = t >> 5;              // 0..15  i-split (one i per 32-lane group)
    const int lb  = (t >> 2) & 7;        // 0..7   l-block (4 l each)
    const int nb  = t & 3;               // 0..3   n-block (n = nb + 4q)
    const int l0  = lb * 4;
    const int sn  = t >> 4;              // staging: n   (0..31)
    const int sil = t & 15;              // staging: i_local (0..15)

    const float* xg = xg_all + (size_t)n0 * ICAPS * KLEN;
    const float* wg = wg_all + (size_t)o * ICAPS * KLEN * LLEN;

    for (int j = t; j < TN * LGS; j += 512) lg[j] = 0.0f;
    __syncthreads();

    for (int iter = 0; iter < 3; ++iter) {
        // ---------------- softmax stats over i, per n ----------------
        {
            const int n = t >> 4, sub = t & 15;
            const float* row = &lg[n * LGS];
            float m = -1e30f;
            for (int j = 0; j < 16; ++j) m = fmaxf(m, row[sub + 16 * j]);
            for (int d = 1; d < 16; d <<= 1) m = fmaxf(m, __shfl_xor(m, d, 16));
            float s = 0.0f;
            for (int j = 0; j < 16; ++j) s += __expf(row[sub + 16 * j] - m);
            for (int d = 1; d < 16; d <<= 1) s += __shfl_xor(s, d, 16);
            if (sub == 0) { stm[n] = m; sti[n] = 1.0f / s; }
        }
        __syncthreads();

        // ---------------- A-pass: s[n][l] = sum_i prob*prior ----------------
        float acc[8][4];
        #pragma unroll
        for (int q = 0; q < 8; ++q)
            #pragma unroll
            for (int r = 0; r < 4; ++r) acc[q][r] = 0.0f;

        for (int st = 0; st < NSTEP; ++st) {
            const int i0 = st * NSTG;
            __syncthreads();
            // stage z = prob[n][i]*x[n][i][k]; one (n,i) row (64B) per thread
            {
                const float e = __expf(lg[sn * LGS + i0 + sil] - stm[sn]) * sti[sn];
                const float4* src = (const float4*)(xg + (size_t)(sn * ICAPS + i0 + sil) * KLEN);
                float4* dst = (float4*)(&xt[sil * XIST + sn * XROW]);
                #pragma unroll
                for (int j = 0; j < 4; ++j) {
                    float4 xv = src[j];
                    xv.x *= e; xv.y *= e; xv.z *= e; xv.w *= e;
                    dst[j] = xv;
                }
            }
            __syncthreads();
            const float* wp = wg + (size_t)(i0 + isp) * (KLEN * LLEN) + l0;
            const float* xp = &xt[isp * XIST];
            #pragma unroll
            for (int k4 = 0; k4 < 4; ++k4) {
                float wr[4][4];
                #pragma unroll
                for (int kk = 0; kk < 4; ++kk)
                    *(float4*)(&wr[kk][0]) = *(const float4*)(wp + (k4 * 4 + kk) * LLEN);
                float xq[8][4];
                #pragma unroll
                for (int q = 0; q < 8; ++q)
                    *(float4*)(&xq[q][0]) = *(const float4*)(xp + (nb + 4 * q) * XROW + k4 * 4);
                #pragma unroll
                for (int kk = 0; kk < 4; ++kk)
                    #pragma unroll
                    for (int q = 0; q < 8; ++q) {
                        const float xv = xq[q][kk];
                        acc[q][0] = fmaf(xv, wr[kk][0], acc[q][0]);
                        acc[q][1] = fmaf(xv, wr[kk][1], acc[q][1]);
                        acc[q][2] = fmaf(xv, wr[kk][2], acc[q][2]);
                        acc[q][3] = fmaf(xv, wr[kk][3], acc[q][3]);
                    }
            }
        }

        // reduce over 16 i-splits: pair in-wave, then 8 wave-partials via LDS
        #pragma unroll
        for (int q = 0; q < 8; ++q)
            #pragma unroll
            for (int r = 0; r < 4; ++r) {
                float v = acc[q][r];
                v += __shfl_xor(v, 32, 64);
                acc[q][r] = v;
            }
        __syncthreads();
        {
            const int wv = t >> 6, lane = t & 63;
            if (lane < 32) {
                float* rb = &xt[wv * 1024 + lane * 32];
                #pragma unroll
                for (int q = 0; q < 8; ++q)
                    #pragma unroll
                    for (int r = 0; r < 4; ++r) rb[q * 4 + r] = acc[q][r];
            }
        }
        __syncthreads();
        for (int c = t; c < 1024; c += 512) {
            const int lane32 = c >> 5;                 // (lb,nb)
            const int qr = c & 31, q = qr >> 2, r = qr & 3;
            const int lbb = (lane32 >> 2) & 7, nbb = lane32 & 3;
            float ssum = 0.0f;
            #pragma unroll
            for (int w8 = 0; w8 < 8; ++w8) ssum += xt[w8 * 1024 + lane32 * 32 + qr];
            sv[(nbb + 4 * q) * SVS + lbb * 4 + r] = ssum;
        }
        __syncthreads();

        // ---------------- squash ----------------
        {
            const int n = t >> 4, sub = t & 15;
            float a = sv[n * SVS + sub];
            float b = sv[n * SVS + sub + 16];
            float sq = a * a + b * b;
            for (int d = 1; d < 16; d <<= 1) sq += __shfl_xor(sq, d, 16);
            const float sc = sqrtf(sq) / (1.0f + sq);
            sv[n * SVS + sub]      = a * sc;
            sv[n * SVS + sub + 16] = b * sc;
        }
        __syncthreads();

        // ---------------- B-pass: logits += sum_l prior*v ----------------
        if (iter < 2) {
            for (int st = 0; st < NSTEP; ++st) {
                const int i0 = st * NSTG;
                __syncthreads();
                {
                    const float4* src = (const float4*)(xg + (size_t)(sn * ICAPS + i0 + sil) * KLEN);
                    float4* dst = (float4*)(&xt[sil * XIST + sn * XROW]);
                    #pragma unroll
                    for (int j = 0; j < 4; ++j) dst[j] = src[j];
                }
                __syncthreads();
                const int i = i0 + isp;
                const float* wp = wg + (size_t)i * (KLEN * LLEN) + l0;
                const float* xp = &xt[isp * XIST];
                float P[8][4];
                #pragma unroll
                for (int q = 0; q < 8; ++q)
                    #pragma unroll
                    for (int r = 0; r < 4; ++r) P[q][r] = 0.0f;
                #pragma unroll
                for (int k4 = 0; k4 < 4; ++k4) {
                    float wr[4][4];
                    #pragma unroll
                    for (int kk = 0; kk < 4; ++kk)
                        *(float4*)(&wr[kk][0]) = *(const float4*)(wp + (k4 * 4 + kk) * LLEN);
                    float xq[8][4];
                    #pragma unroll
                    for (int q = 0; q < 8; ++q)
                        *(float4*)(&xq[q][0]) = *(const float4*)(xp + (nb + 4 * q) * XROW + k4 * 4);
                    #pragma unroll
                    for (int kk = 0; kk < 4; ++kk)
                        #pragma unroll
                        for (int q = 0; q < 8; ++q) {
                            const float xv = xq[q][kk];
                            P[q][0] = fmaf(xv, wr[kk][0], P[q][0]);
                            P[q][1] = fmaf(xv, wr[kk][1], P[q][1]);
                            P[q][2] = fmaf(xv, wr[kk][2], P[q][2]);
                            P[q][3] = fmaf(xv, wr[kk][3], P[q][3]);
                        }
                }
                // delta[n][i] = sum_l P*v ; reduce over 8 l-blocks (lanes xor 4,8,16)
                #pragma unroll
                for (int q = 0; q < 8; ++q) {
                    const float* vp = &sv[(nb + 4 * q) * SVS + l0];
                    float d0 = P[q][0] * vp[0] + P[q][1] * vp[1]
                             + P[q][2] * vp[2] + P[q][3] * vp[3];
                    d0 += __shfl_xor(d0, 4, 64);
                    d0 += __shfl_xor(d0, 8, 64);
                    d0 += __shfl_xor(d0, 16, 64);
                    if (lb == 0) lg[(nb + 4 * q) * LGS + i] += d0;
                }
            }
            __syncthreads();
        }
    }

    // ---------------- output: out[n0+n][o][l] = v[n][l] ----------------
    for (int c = t; c < 1024; c += 512) {
        const int n = c >> 5, l = c & 31;
        out[((size_t)(n0 + n) * OCAPS + o) * LLEN + l] = sv[n * SVS + l];
    }
}

extern "C" void kernel_launch(void* const* d_in, const int* in_sizes, int n_in,
                              void* d_out, int out_size, void* d_ws, size_t ws_size,
                              hipStream_t stream) {
    const float* x = (const float*)d_in[0];   // [64,256,16]
    const float* w = (const float*)d_in[1];   // [128,256,16,32]
    float* out = (float*)d_out;               // [64,128,32]
    caps_route<<<dim3(OCAPS * 2), dim3(512), 0, stream>>>(x, w, out);
}

// Round 3
// 262.195 us; speedup vs baseline: 2.7915x; 2.7915x over previous
//
#include <hip/hip_runtime.h>

// CapsuleLinear dynamic routing, fused, fp32, 3 weight passes (was 5).
// N=64, I=256, O=128, K=16, L=32, 3 routing iters.
// Grid 512 = 128 o x 4 n-quarters (TN=16), 512 thr. LDS ~60KB + VGPR<=128
// -> 2 blocks/CU. Softmax without max-subtraction (logits bounded ~30) lets
// each iteration's logit-update fuse with the NEXT iteration's weighted sum:
//   A0: s0 = (1/256) sum_i P_i            (probs uniform, logits==0)
//   M1: per i: P_i, d=P_i.v0, lg=d, e=exp(lg), u+=e*P_i, z+=e -> s1=u/z
//   M2: same with v1 and lg+=d (no store)                     -> s2=u/z -> out

#define ICAPS 256
#define OCAPS 128
#define KLEN  16
#define LLEN  32
#define TN    16
#define LGS   257              // logits row stride
#define XROW  20               // 16 k + 4 pad (80B, 16B-aligned)
#define XIST  (TN * XROW + 4)  // 324: per-i stride, breaks bank periodicity
#define SVS   33
#define RBS   33               // reduce-buffer lane stride (conflict-free)
#define NSTG  32               // i per stage
#define NSTEP (ICAPS / NSTG)   // 8

__global__ __launch_bounds__(512, 2)
void caps_route(const float* __restrict__ xg_all,
                const float* __restrict__ wg_all,
                float* __restrict__ out) {
    __shared__ float lg[TN * LGS];     // 16.4 KB logits
    __shared__ float xt[NSTG * XIST];  // 41.5 KB x staging / reduce buffer
    __shared__ float sv[TN * SVS];     // 2.1 KB  s then v
    __shared__ float zz[8][TN];        // per-wave softmax-denominator partials
    __shared__ float zinv[TN];

    const int t   = threadIdx.x;
    const int o   = blockIdx.x & 127;          // same-o blocks share an XCD
    const int n0  = (blockIdx.x >> 7) * TN;
    const int isp = t >> 4;                    // 0..31 i-split
    const int lb  = (t >> 2) & 3;              // 0..3  l-block (8 l)
    const int nb  = t & 3;                     // 0..3  n-block (n = nb+4q)
    const int l0  = lb * 8;

    const float* xg = xg_all + (size_t)n0 * ICAPS * KLEN;
    const float* wg = wg_all + (size_t)o * ICAPS * KLEN * LLEN;

    for (int pass = 0; pass < 3; ++pass) {
        float u[4][8];
        float zq[4] = {0.f, 0.f, 0.f, 0.f};
        #pragma unroll
        for (int q = 0; q < 4; ++q)
            #pragma unroll
            for (int r = 0; r < 8; ++r) u[q][r] = 0.f;

        for (int st = 0; st < NSTEP; ++st) {
            const int i0 = st * NSTG;
            __syncthreads();
            // stage raw x [32 i][16 n][16 k]; fully coalesced float4 loads
            #pragma unroll
            for (int j = 0; j < 4; ++j) {
                const int g   = j * 512 + t;       // n-major flat float4 index
                const int n   = g >> 7;
                const int rem = g & 127;
                const int il  = rem >> 2;
                const int k4c = rem & 3;
                *(float4*)(&xt[il * XIST + n * XROW + k4c * 4]) =
                    *(const float4*)(xg + (size_t)(n * ICAPS + i0 + il) * KLEN + k4c * 4);
            }
            __syncthreads();

            const int i = i0 + isp;
            const float* wp = wg + (size_t)i * (KLEN * LLEN) + l0;
            const float* xp = &xt[isp * XIST];
            float P[4][8];
            #pragma unroll
            for (int q = 0; q < 4; ++q)
                #pragma unroll
                for (int r = 0; r < 8; ++r) P[q][r] = 0.f;

            #pragma unroll
            for (int k4 = 0; k4 < 4; ++k4) {
                float xq[4][4];
                #pragma unroll
                for (int q = 0; q < 4; ++q)
                    *(float4*)(&xq[q][0]) = *(const float4*)(xp + (nb + 4 * q) * XROW + k4 * 4);
                #pragma unroll
                for (int kk = 0; kk < 4; ++kk) {
                    const int k = k4 * 4 + kk;
                    const float4 wa = *(const float4*)(wp + k * LLEN);
                    const float4 wb = *(const float4*)(wp + k * LLEN + 4);
                    #pragma unroll
                    for (int q = 0; q < 4; ++q) {
                        const float xv = xq[q][kk];
                        P[q][0] = fmaf(xv, wa.x, P[q][0]);
                        P[q][1] = fmaf(xv, wa.y, P[q][1]);
                        P[q][2] = fmaf(xv, wa.z, P[q][2]);
                        P[q][3] = fmaf(xv, wa.w, P[q][3]);
                        P[q][4] = fmaf(xv, wb.x, P[q][4]);
                        P[q][5] = fmaf(xv, wb.y, P[q][5]);
                        P[q][6] = fmaf(xv, wb.z, P[q][6]);
                        P[q][7] = fmaf(xv, wb.w, P[q][7]);
                    }
                }
            }

            if (pass == 0) {
                #pragma unroll
                for (int q = 0; q < 4; ++q)
                    #pragma unroll
                    for (int r = 0; r < 8; ++r) u[q][r] += P[q][r];
            } else {
                #pragma unroll
                for (int q = 0; q < 4; ++q) {
                    const float* vp = &sv[(nb + 4 * q) * SVS + l0];
                    float d = P[q][0] * vp[0] + P[q][1] * vp[1] + P[q][2] * vp[2] + P[q][3] * vp[3]
                            + P[q][4] * vp[4] + P[q][5] * vp[5] + P[q][6] * vp[6] + P[q][7] * vp[7];
                    d += __shfl_xor(d, 4);     // reduce over the 4 l-blocks;
                    d += __shfl_xor(d, 8);     // butterfly -> all lanes have it
                    float lnew = d;
                    if (pass == 2) lnew += lg[(nb + 4 * q) * LGS + i];   // lg from M1
                    else if (lb == 0) lg[(nb + 4 * q) * LGS + i] = lnew; // store for M2
                    const float e = __expf(lnew);
                    zq[q] += e;
                    #pragma unroll
                    for (int r = 0; r < 8; ++r) u[q][r] = fmaf(e, P[q][r], u[q][r]);
                }
            }
        }

        // reduce u (and z) over 32 i-splits: 4 in-wave, 8 waves via LDS
        #pragma unroll
        for (int q = 0; q < 4; ++q) {
            #pragma unroll
            for (int r = 0; r < 8; ++r) {
                float v = u[q][r];
                v += __shfl_xor(v, 16);
                v += __shfl_xor(v, 32);
                u[q][r] = v;
            }
            float z = zq[q];
            z += __shfl_xor(z, 16);
            z += __shfl_xor(z, 32);
            zq[q] = z;
        }
        __syncthreads();                        // xt free -> reduce buffer
        {
            const int wv = t >> 6, lane = t & 63;
            if (lane < 16) {
                float* rb = &xt[wv * (16 * RBS) + lane * RBS];
                #pragma unroll
                for (int q = 0; q < 4; ++q)
                    #pragma unroll
                    for (int r = 0; r < 8; ++r) rb[q * 8 + r] = u[q][r];
            }
            if (pass > 0 && lane < 4) {
                #pragma unroll
                for (int q = 0; q < 4; ++q) zz[wv][lane + 4 * q] = zq[q];
            }
        }
        __syncthreads();
        {
            const int low4 = t >> 5, qr = t & 31;
            const int qq = qr >> 3, rr = qr & 7;
            const int lbb = low4 >> 2, nbb = low4 & 3;
            float ssum = 0.f;
            #pragma unroll
            for (int w8 = 0; w8 < 8; ++w8) ssum += xt[w8 * (16 * RBS) + low4 * RBS + qr];
            sv[(nbb + 4 * qq) * SVS + lbb * 8 + rr] = ssum;
        }
        if (t < TN) {
            if (pass == 0) zinv[t] = 1.0f / 256.0f;
            else {
                float zs = 0.f;
                #pragma unroll
                for (int w8 = 0; w8 < 8; ++w8) zs += zz[w8][t];
                zinv[t] = 1.0f / zs;
            }
        }
        __syncthreads();

        // squash: s = u*zinv; v = s * ||s||/(1+||s||^2)
        {
            const int n = t >> 5, l = t & 31;
            const float val = sv[n * SVS + l] * zinv[n];
            float sq = val * val;
            #pragma unroll
            for (int m = 1; m < 32; m <<= 1) sq += __shfl_xor(sq, m, 32);
            const float sc = sqrtf(sq) / (1.0f + sq);
            if (pass == 2)
                out[((size_t)(n0 + n) * OCAPS + o) * LLEN + l] = val * sc;
            else
                sv[n * SVS + l] = val * sc;    // own element only; next read after barrier
        }
    }
}

extern "C" void kernel_launch(void* const* d_in, const int* in_sizes, int n_in,
                              void* d_out, int out_size, void* d_ws, size_t ws_size,
                              hipStream_t stream) {
    const float* x = (const float*)d_in[0];   // [64,256,16]
    const float* w = (const float*)d_in[1];   // [128,256,16,32]
    float* outp = (float*)d_out;              // [64,128,32]
    caps_route<<<dim3(512), dim3(512), 0, stream>>>(x, w, outp);
}

// Round 4
// 151.377 us; speedup vs baseline: 4.8351x; 1.7321x over previous
//
#include <hip/hip_runtime.h>

// CapsuleLinear dynamic routing via MFMA. N=64, I=256, O=128, K=16, L=32, 3 iters.
//
// caps_prep: converts w (and x) fp32 -> bf16 hi/lo, pre-swizzled into
//   v_mfma_f32_32x32x16_bf16 fragment order in d_ws (A = w with M=l rows,
//   B = x with N=n cols). 65MB; HBM-bound.
// caps_main: grid 256 = (o 0..127) x (n-half 0..1), 512 thr (8 waves).
//   Per i: 3 MFMAs (hi*hi + hi*lo + lo*hi ~ fp32) give P[l 32][n 32];
//   D layout col=lane&31=n, row l=(r&3)+8*(r>>2)+4*(lane>>5) -> the routing
//   dot d[n]=sum_l P*v is 16 lane-local FMAs + shfl_xor(32).
//   Fused 3-pass routing as in round 3 (no-max softmax, logits in LDS [i][n]).
// Fallback (ws too small): round-3 VALU kernel.

#define ICAPS 256
#define OCAPS 128
#define WS_WH 0ull
#define WS_WL 33554432ull
#define WS_XH 67108864ull
#define WS_XL 67633152ull
#define WS_NEED 68157440ull

typedef __attribute__((ext_vector_type(8))) short s16x8;
typedef __attribute__((ext_vector_type(16))) float f32x16;

__device__ inline unsigned bfbits(float f) {   // RNE bf16, returned as fp32 bit pattern
    unsigned u = __float_as_uint(f);
    return (u + 0x7FFFu + ((u >> 16) & 1u)) & 0xFFFF0000u;
}

// ---------------- prep: fp32 -> bf16 hi/lo fragments ----------------
__global__ __launch_bounds__(256)
void caps_prep(const float* __restrict__ x, const float* __restrict__ w,
               unsigned char* __restrict__ ws) {
    const int wv = threadIdx.x >> 6, lane = threadIdx.x & 63;
    unsigned* WH = (unsigned*)(ws + WS_WH);
    unsigned* WL = (unsigned*)(ws + WS_WL);
    unsigned* XH = (unsigned*)(ws + WS_XH);
    unsigned* XL = (unsigned*)(ws + WS_XL);

    float f[8];
    if (blockIdx.x < 8192) {                 // w tiles: id = o*256+i
        const int id = blockIdx.x * 4 + wv;
        const int l = lane & 31, kb = (lane >> 5) * 8;
        const float* src = w + ((size_t)id * 16 + kb) * 32 + l;
        #pragma unroll
        for (int j = 0; j < 8; ++j) f[j] = src[j * 32];
        unsigned h[4], g[4];
        #pragma unroll
        for (int c = 0; c < 4; ++c) {
            unsigned b0 = bfbits(f[2 * c]), b1 = bfbits(f[2 * c + 1]);
            h[c] = (b0 >> 16) | (b1 & 0xFFFF0000u);
            float l0 = f[2 * c] - __uint_as_float(b0);
            float l1 = f[2 * c + 1] - __uint_as_float(b1);
            g[c] = (bfbits(l0) >> 16) | (bfbits(l1) & 0xFFFF0000u);
        }
        const size_t o4 = (size_t)(id * 64 + lane) * 4;
        *(uint4*)(WH + o4) = make_uint4(h[0], h[1], h[2], h[3]);
        *(uint4*)(WL + o4) = make_uint4(g[0], g[1], g[2], g[3]);
    } else {                                  // x tiles: id = nh*256+i
        const int id = (blockIdx.x - 8192) * 4 + wv;
        const int nh = id >> 8, i = id & 255;
        const int np = lane & 31, kb = (lane >> 5) * 8;
        const float* src = x + ((size_t)(nh * 32 + np) * ICAPS + i) * 16 + kb;
        float4 a = *(const float4*)src, b = *(const float4*)(src + 4);
        f[0] = a.x; f[1] = a.y; f[2] = a.z; f[3] = a.w;
        f[4] = b.x; f[5] = b.y; f[6] = b.z; f[7] = b.w;
        unsigned h[4], g[4];
        #pragma unroll
        for (int c = 0; c < 4; ++c) {
            unsigned b0 = bfbits(f[2 * c]), b1 = bfbits(f[2 * c + 1]);
            h[c] = (b0 >> 16) | (b1 & 0xFFFF0000u);
            float l0 = f[2 * c] - __uint_as_float(b0);
            float l1 = f[2 * c + 1] - __uint_as_float(b1);
            g[c] = (bfbits(l0) >> 16) | (bfbits(l1) & 0xFFFF0000u);
        }
        const size_t o4 = (size_t)(id * 64 + lane) * 4;
        *(uint4*)(XH + o4) = make_uint4(h[0], h[1], h[2], h[3]);
        *(uint4*)(XL + o4) = make_uint4(g[0], g[1], g[2], g[3]);
    }
}

// ---------------- main: MFMA routing ----------------
__global__ __launch_bounds__(512)
void caps_main(const unsigned char* __restrict__ ws, float* __restrict__ out) {
    __shared__ float lg[ICAPS * 32];      // [i][n] 32 KB
    __shared__ float slab[8 * 1280];      // per-wave u partials, 40 KB (lane stride 20)
    __shared__ float svv[32 * 33];        // s then v
    __shared__ float zz[8 * 32];
    __shared__ float zinv[32];

    const int t = threadIdx.x, wv = t >> 6, lane = t & 63;
    const int o = blockIdx.x & 127, nh = blockIdx.x >> 7;   // o-pairs share an XCD
    const int n = lane & 31, half = lane >> 5;

    const s16x8* WHp = (const s16x8*)(ws + WS_WH) + (size_t)o * ICAPS * 64 + lane;
    const s16x8* WLp = (const s16x8*)(ws + WS_WL) + (size_t)o * ICAPS * 64 + lane;
    const s16x8* XHp = (const s16x8*)(ws + WS_XH) + (size_t)nh * ICAPS * 64 + lane;
    const s16x8* XLp = (const s16x8*)(ws + WS_XL) + (size_t)nh * ICAPS * 64 + lane;

    float vr[16];
    const int ibase = wv * 32;

    for (int pass = 0; pass < 3; ++pass) {
        float uacc[16];
        #pragma unroll
        for (int r = 0; r < 16; ++r) uacc[r] = 0.f;
        float z = 0.f;

        for (int ii = 0; ii < 32; ++ii) {
            const int i = ibase + ii;
            const s16x8 ah = WHp[(size_t)i * 64];
            const s16x8 al = WLp[(size_t)i * 64];
            const s16x8 bh = XHp[(size_t)i * 64];
            const s16x8 bl = XLp[(size_t)i * 64];
            f32x16 P = {};
            P = __builtin_amdgcn_mfma_f32_32x32x16_bf16(al, bh, P, 0, 0, 0);
            P = __builtin_amdgcn_mfma_f32_32x32x16_bf16(ah, bl, P, 0, 0, 0);
            P = __builtin_amdgcn_mfma_f32_32x32x16_bf16(ah, bh, P, 0, 0, 0);

            if (pass == 0) {
                #pragma unroll
                for (int r = 0; r < 16; ++r) uacc[r] += P[r];
            } else {
                float da = P[0] * vr[0];
                float db = P[8] * vr[8];
                #pragma unroll
                for (int r = 1; r < 8; ++r) {
                    da = fmaf(P[r], vr[r], da);
                    db = fmaf(P[r + 8], vr[r + 8], db);
                }
                float d = da + db;
                d += __shfl_xor(d, 32);                 // combine l-halves
                if (pass == 1) {
                    if (half == 0) lg[i * 32 + n] = d;  // store logits for pass 2
                } else {
                    d += lg[i * 32 + n];
                }
                const float e = __expf(d);
                z += e;
                #pragma unroll
                for (int r = 0; r < 16; ++r) uacc[r] = fmaf(e, P[r], uacc[r]);
            }
        }

        // ---- cross-wave reduce of u (and z) ----
        #pragma unroll
        for (int c = 0; c < 4; ++c)
            *(float4*)(&slab[wv * 1280 + lane * 20 + c * 4]) =
                make_float4(uacc[4 * c], uacc[4 * c + 1], uacc[4 * c + 2], uacc[4 * c + 3]);
        if (pass > 0 && half == 0) zz[wv * 32 + n] = z;
        __syncthreads();

        #pragma unroll
        for (int hh = 0; hh < 2; ++hh) {
            const int e = t + hh * 512;
            const int lw = e >> 4, r = e & 15;
            float s = 0.f;
            #pragma unroll
            for (int w8 = 0; w8 < 8; ++w8) s += slab[w8 * 1280 + lw * 20 + r];
            const int nn = lw & 31, ll = (r & 3) + 8 * (r >> 2) + 4 * (lw >> 5);
            svv[nn * 33 + ll] = s;
        }
        if (t < 32) {
            if (pass == 0) zinv[t] = 1.0f / 256.0f;
            else {
                float zs = 0.f;
                #pragma unroll
                for (int w8 = 0; w8 < 8; ++w8) zs += zz[w8 * 32 + t];
                zinv[t] = 1.0f / zs;
            }
        }
        __syncthreads();

        // ---- squash (and output on last pass) ----
        {
            const int nq = t >> 4, sub = t & 15;
            const float a = svv[nq * 33 + sub] * zinv[nq];
            const float b = svv[nq * 33 + sub + 16] * zinv[nq];
            float sq = a * a + b * b;
            #pragma unroll
            for (int m = 1; m < 16; m <<= 1) sq += __shfl_xor(sq, m, 16);
            const float sc = sqrtf(sq) / (1.0f + sq);
            if (pass == 2) {
                const int ng = nh * 32 + nq;
                out[((size_t)ng * OCAPS + o) * 32 + sub] = a * sc;
                out[((size_t)ng * OCAPS + o) * 32 + sub + 16] = b * sc;
            } else {
                svv[nq * 33 + sub] = a * sc;
                svv[nq * 33 + sub + 16] = b * sc;
            }
        }
        if (pass < 2) {
            __syncthreads();
            #pragma unroll
            for (int r = 0; r < 16; ++r) {
                const int l = (r & 3) + 8 * (r >> 2) + 4 * half;
                vr[r] = svv[n * 33 + l];
            }
        }
    }
}

// ---------------- fallback (round-3 kernel) ----------------
#define KLEN  16
#define LLEN  32
#define TN    16
#define LGS   257
#define XROW  20
#define XIST  (TN * XROW + 4)
#define SVS   33
#define RBS   33
#define NSTG  32
#define NSTEP (ICAPS / NSTG)

__global__ __launch_bounds__(512, 2)
void caps_route_fb(const float* __restrict__ xg_all,
                   const float* __restrict__ wg_all,
                   float* __restrict__ out) {
    __shared__ float lg[TN * LGS];
    __shared__ float xt[NSTG * XIST];
    __shared__ float sv[TN * SVS];
    __shared__ float zz[8][TN];
    __shared__ float zinv[TN];

    const int t   = threadIdx.x;
    const int o   = blockIdx.x & 127;
    const int n0  = (blockIdx.x >> 7) * TN;
    const int isp = t >> 4;
    const int lb  = (t >> 2) & 3;
    const int nb  = t & 3;
    const int l0  = lb * 8;

    const float* xg = xg_all + (size_t)n0 * ICAPS * KLEN;
    const float* wg = wg_all + (size_t)o * ICAPS * KLEN * LLEN;

    for (int pass = 0; pass < 3; ++pass) {
        float u[4][8];
        float zq[4] = {0.f, 0.f, 0.f, 0.f};
        #pragma unroll
        for (int q = 0; q < 4; ++q)
            #pragma unroll
            for (int r = 0; r < 8; ++r) u[q][r] = 0.f;

        for (int st = 0; st < NSTEP; ++st) {
            const int i0 = st * NSTG;
            __syncthreads();
            #pragma unroll
            for (int j = 0; j < 4; ++j) {
                const int g   = j * 512 + t;
                const int n   = g >> 7;
                const int rem = g & 127;
                const int il  = rem >> 2;
                const int k4c = rem & 3;
                *(float4*)(&xt[il * XIST + n * XROW + k4c * 4]) =
                    *(const float4*)(xg + (size_t)(n * ICAPS + i0 + il) * KLEN + k4c * 4);
            }
            __syncthreads();

            const int i = i0 + isp;
            const float* wp = wg + (size_t)i * (KLEN * LLEN) + l0;
            const float* xp = &xt[isp * XIST];
            float P[4][8];
            #pragma unroll
            for (int q = 0; q < 4; ++q)
                #pragma unroll
                for (int r = 0; r < 8; ++r) P[q][r] = 0.f;

            #pragma unroll
            for (int k4 = 0; k4 < 4; ++k4) {
                float xq[4][4];
                #pragma unroll
                for (int q = 0; q < 4; ++q)
                    *(float4*)(&xq[q][0]) = *(const float4*)(xp + (nb + 4 * q) * XROW + k4 * 4);
                #pragma unroll
                for (int kk = 0; kk < 4; ++kk) {
                    const int k = k4 * 4 + kk;
                    const float4 wa = *(const float4*)(wp + k * LLEN);
                    const float4 wb = *(const float4*)(wp + k * LLEN + 4);
                    #pragma unroll
                    for (int q = 0; q < 4; ++q) {
                        const float xv = xq[q][kk];
                        P[q][0] = fmaf(xv, wa.x, P[q][0]);
                        P[q][1] = fmaf(xv, wa.y, P[q][1]);
                        P[q][2] = fmaf(xv, wa.z, P[q][2]);
                        P[q][3] = fmaf(xv, wa.w, P[q][3]);
                        P[q][4] = fmaf(xv, wb.x, P[q][4]);
                        P[q][5] = fmaf(xv, wb.y, P[q][5]);
                        P[q][6] = fmaf(xv, wb.z, P[q][6]);
                        P[q][7] = fmaf(xv, wb.w, P[q][7]);
                    }
                }
            }

            if (pass == 0) {
                #pragma unroll
                for (int q = 0; q < 4; ++q)
                    #pragma unroll
                    for (int r = 0; r < 8; ++r) u[q][r] += P[q][r];
            } else {
                #pragma unroll
                for (int q = 0; q < 4; ++q) {
                    const float* vp = &sv[(nb + 4 * q) * SVS + l0];
                    float d = P[q][0] * vp[0] + P[q][1] * vp[1] + P[q][2] * vp[2] + P[q][3] * vp[3]
                            + P[q][4] * vp[4] + P[q][5] * vp[5] + P[q][6] * vp[6] + P[q][7] * vp[7];
                    d += __shfl_xor(d, 4);
                    d += __shfl_xor(d, 8);
                    float lnew = d;
                    if (pass == 2) lnew += lg[(nb + 4 * q) * LGS + i];
                    else if (lb == 0) lg[(nb + 4 * q) * LGS + i] = lnew;
                    const float e = __expf(lnew);
                    zq[q] += e;
                    #pragma unroll
                    for (int r = 0; r < 8; ++r) u[q][r] = fmaf(e, P[q][r], u[q][r]);
                }
            }
        }

        #pragma unroll
        for (int q = 0; q < 4; ++q) {
            #pragma unroll
            for (int r = 0; r < 8; ++r) {
                float v = u[q][r];
                v += __shfl_xor(v, 16);
                v += __shfl_xor(v, 32);
                u[q][r] = v;
            }
            float zv = zq[q];
            zv += __shfl_xor(zv, 16);
            zv += __shfl_xor(zv, 32);
            zq[q] = zv;
        }
        __syncthreads();
        {
            const int wvv = t >> 6, lane = t & 63;
            if (lane < 16) {
                float* rb = &xt[wvv * (16 * RBS) + lane * RBS];
                #pragma unroll
                for (int q = 0; q < 4; ++q)
                    #pragma unroll
                    for (int r = 0; r < 8; ++r) rb[q * 8 + r] = u[q][r];
            }
            if (pass > 0 && lane < 4) {
                #pragma unroll
                for (int q = 0; q < 4; ++q) zz[wvv][lane + 4 * q] = zq[q];
            }
        }
        __syncthreads();
        {
            const int low4 = t >> 5, qr = t & 31;
            const int qq = qr >> 3, rr = qr & 7;
            const int lbb = low4 >> 2, nbb = low4 & 3;
            float ssum = 0.f;
            #pragma unroll
            for (int w8 = 0; w8 < 8; ++w8) ssum += xt[w8 * (16 * RBS) + low4 * RBS + qr];
            sv[(nbb + 4 * qq) * SVS + lbb * 8 + rr] = ssum;
        }
        if (t < TN) {
            if (pass == 0) zinv[t] = 1.0f / 256.0f;
            else {
                float zs = 0.f;
                #pragma unroll
                for (int w8 = 0; w8 < 8; ++w8) zs += zz[w8][t];
                zinv[t] = 1.0f / zs;
            }
        }
        __syncthreads();
        {
            const int n = t >> 5, l = t & 31;
            const float val = sv[n * SVS + l] * zinv[n];
            float sq = val * val;
            #pragma unroll
            for (int m = 1; m < 32; m <<= 1) sq += __shfl_xor(sq, m, 32);
            const float sc = sqrtf(sq) / (1.0f + sq);
            if (pass == 2)
                out[((size_t)(n0 + n) * OCAPS + o) * LLEN + l] = val * sc;
            else
                sv[n * SVS + l] = val * sc;
        }
    }
}

extern "C" void kernel_launch(void* const* d_in, const int* in_sizes, int n_in,
                              void* d_out, int out_size, void* d_ws, size_t ws_size,
                              hipStream_t stream) {
    const float* x = (const float*)d_in[0];   // [64,256,16]
    const float* w = (const float*)d_in[1];   // [128,256,16,32]
    float* outp = (float*)d_out;              // [64,128,32]
    if (ws_size >= WS_NEED) {
        caps_prep<<<dim3(8320), dim3(256), 0, stream>>>(x, w, (unsigned char*)d_ws);
        caps_main<<<dim3(256), dim3(512), 0, stream>>>((const unsigned char*)d_ws, outp);
    } else {
        caps_route_fb<<<dim3(512), dim3(512), 0, stream>>>(x, w, outp);
    }
}